// Round 6
// baseline (774.286 us; speedup 1.0000x reference)
//
#include <hip/hip_runtime.h>
#include <hip/hip_bf16.h>

#define LRELU(x) ((x) > 0.0f ? (x) : 0.01f * (x))

typedef __attribute__((ext_vector_type(4))) short bf16x4;
typedef __attribute__((ext_vector_type(4))) float f32x4;

// Monotonic float -> uint encoding for max-atomics on pooled.
__device__ __forceinline__ unsigned fenc(float f) {
    unsigned u = __float_as_uint(f);
    return (u & 0x80000000u) ? ~u : (u | 0x80000000u);
}
__device__ __forceinline__ float fdec(unsigned u) {
    return (u & 0x80000000u) ? __uint_as_float(u & 0x7fffffffu) : __uint_as_float(~u);
}
// f32 -> bf16 RNE via HIP intrinsic (lets compiler pair into v_cvt_pk_bf16_f32)
__device__ __forceinline__ short f2bf(float f) {
    __hip_bfloat16 b = __float2bfloat16(f);
    return *reinterpret_cast<short*>(&b);
}
__device__ __forceinline__ float bf2f(short s) {
    return __uint_as_float(((unsigned)(unsigned short)s) << 16);
}

__device__ __forceinline__ f32x4 mfma16(bf16x4 a, bf16x4 b, f32x4 c) {
#if __has_builtin(__builtin_amdgcn_mfma_f32_16x16x16bf16_1k)
    return __builtin_amdgcn_mfma_f32_16x16x16bf16_1k(a, b, c, 0, 0, 0);
#else
    asm("v_mfma_f32_16x16x16_bf16 %0, %1, %2, %0" : "+v"(c) : "v"(a), "v"(b));
    return c;
#endif
}

// ---------------------------------------------------------------------------
// CSR build step 1: histogram of dst
// ---------------------------------------------------------------------------
__global__ __launch_bounds__(256) void hist_kernel(const int* __restrict__ ei,
                                                   int* __restrict__ deg, int E)
{
    const int stride = gridDim.x * blockDim.x;
    for (int e = blockIdx.x * blockDim.x + threadIdx.x; e < E; e += stride)
        atomicAdd(&deg[ei[E + e]], 1);
}

// ---------------------------------------------------------------------------
// CSR build step 2: single-block exclusive scan (4 elems/thread per tile)
// ---------------------------------------------------------------------------
__global__ __launch_bounds__(1024) void scan_kernel(const int* __restrict__ deg,
                                                    int* __restrict__ rowptr,
                                                    int* __restrict__ cursor, int N)
{
    __shared__ int wsum[16];
    __shared__ int tiletot;
    const int lane = threadIdx.x & 63;
    const int w    = threadIdx.x >> 6;
    int carry = 0;
    for (int base = 0; base < N; base += 4096) {
        const int i = base + (int)threadIdx.x * 4;
        int4 v = {0, 0, 0, 0};
        if (i + 3 < N) {
            v = *reinterpret_cast<const int4*>(deg + i);
        } else {
            if (i < N)     v.x = deg[i];
            if (i + 1 < N) v.y = deg[i + 1];
            if (i + 2 < N) v.z = deg[i + 2];
        }
        const int tot = v.x + v.y + v.z + v.w;
        int s = tot;
#pragma unroll
        for (int off = 1; off < 64; off <<= 1) {
            int t = __shfl_up(s, off);
            if (lane >= off) s += t;
        }
        if (lane == 63) wsum[w] = s;
        __syncthreads();
        if (threadIdx.x == 0) {
            int acc = 0;
#pragma unroll
            for (int k = 0; k < 16; ++k) { int t = wsum[k]; wsum[k] = acc; acc += t; }
            tiletot = acc;
        }
        __syncthreads();
        const int excl = carry + wsum[w] + (s - tot);
        int4 o;
        o.x = excl; o.y = excl + v.x; o.z = o.y + v.y; o.w = o.z + v.z;
        if (i + 3 < N) {
            *reinterpret_cast<int4*>(rowptr + i) = o;
            *reinterpret_cast<int4*>(cursor + i) = o;
        } else {
            if (i < N)     { rowptr[i] = o.x;     cursor[i] = o.x; }
            if (i + 1 < N) { rowptr[i + 1] = o.y; cursor[i + 1] = o.y; }
            if (i + 2 < N) { rowptr[i + 2] = o.z; cursor[i + 2] = o.z; }
        }
        carry += tiletot;
        __syncthreads();
    }
    if (threadIdx.x == 0) rowptr[N] = carry;
}

// ---------------------------------------------------------------------------
// Scatter {src, edge_id} (8B) into dst-sorted order. Minimal scattered bytes;
// eattr itself is never permuted (edge_mlp gathers it via the id).
// ---------------------------------------------------------------------------
__global__ __launch_bounds__(256) void scatter_kernel(
    const int* __restrict__ ei, int* __restrict__ cursor,
    int2* __restrict__ pack, int E)
{
    const int stride = gridDim.x * blockDim.x;
    for (int e = blockIdx.x * blockDim.x + threadIdx.x; e < E; e += stride) {
        const int d = ei[E + e];
        const int p = atomicAdd(&cursor[d], 1);
        pack[p] = make_int2(ei[e], e);
    }
}

// ---------------------------------------------------------------------------
// Edge embedding MLP via MFMA: iterates dst-sorted positions, GATHERS the
// f32 edge attrs via pack[].y, writes ea rows coalesced at the sorted index.
// D-frag: col(lane&15)=edge slot, row ch = t*16 + (lane>>4)*4 + j.
// ---------------------------------------------------------------------------
__global__ __launch_bounds__(256) void edge_mlp_mfma(
    const float* __restrict__ eattr, const int2* __restrict__ pack,
    const float* __restrict__ W1, const float* __restrict__ b1,
    const float* __restrict__ W2, const float* __restrict__ b2,
    const float* __restrict__ W3, const float* __restrict__ b3,
    short* __restrict__ eout, int E)
{
    const int lane = threadIdx.x & 63;
    const int el   = lane & 15;
    const int g    = lane >> 4;

    bf16x4 w1f[4];
    bf16x4 w2f[4][4];
    bf16x4 w3f[4][4];
    f32x4  bf1[4], bf2[4], bf3[4];
#pragma unroll
    for (int t = 0; t < 4; ++t) {
        const int c = t * 16 + el;
#pragma unroll
        for (int j = 0; j < 4; ++j) {
            const int k = g * 4 + j;
            w1f[t][j] = (k < 8) ? f2bf(W1[k * 64 + c]) : (short)0;
        }
#pragma unroll
        for (int kb = 0; kb < 4; ++kb) {
#pragma unroll
            for (int j = 0; j < 4; ++j) {
                const int k = kb * 16 + g * 4 + j;
                w2f[t][kb][j] = f2bf(W2[k * 64 + c]);
                w3f[t][kb][j] = f2bf(W3[k * 64 + c]);
            }
        }
        const float4 v1 = *reinterpret_cast<const float4*>(b1 + t * 16 + g * 4);
        const float4 v2 = *reinterpret_cast<const float4*>(b2 + t * 16 + g * 4);
        const float4 v3 = *reinterpret_cast<const float4*>(b3 + t * 16 + g * 4);
        bf1[t][0] = v1.x; bf1[t][1] = v1.y; bf1[t][2] = v1.z; bf1[t][3] = v1.w;
        bf2[t][0] = v2.x; bf2[t][1] = v2.y; bf2[t][2] = v2.z; bf2[t][3] = v2.w;
        bf3[t][0] = v3.x; bf3[t][1] = v3.y; bf3[t][2] = v3.z; bf3[t][3] = v3.w;
    }

    const int nblk = (E + 15) >> 4;
    const int wid  = (int)((blockIdx.x * blockDim.x + threadIdx.x) >> 6);
    const int nw   = (int)((gridDim.x * blockDim.x) >> 6);

    for (int eb = wid; eb < nblk; eb += nw) {
        const int e  = eb * 16 + el;
        const int ec = min(e, E - 1);
        const int eid = pack[ec].y;     // 4 lanes per el-group read same addr

        bf16x4 bfr = (bf16x4)0;
        if (g < 2) {
            const float4 av = *reinterpret_cast<const float4*>(eattr + (size_t)eid * 8 + g * 4);
            bfr[0] = f2bf(av.x); bfr[1] = f2bf(av.y);
            bfr[2] = f2bf(av.z); bfr[3] = f2bf(av.w);
        }

        f32x4  acc[4];
        bf16x4 act[4];

#pragma unroll
        for (int t = 0; t < 4; ++t) acc[t] = mfma16(w1f[t], bfr, bf1[t]);
#pragma unroll
        for (int t = 0; t < 4; ++t)
#pragma unroll
            for (int j = 0; j < 4; ++j) act[t][j] = f2bf(fmaxf(acc[t][j], 0.0f));

#pragma unroll
        for (int t = 0; t < 4; ++t) {
            f32x4 a = bf2[t];
#pragma unroll
            for (int kb = 0; kb < 4; ++kb) a = mfma16(w2f[t][kb], act[kb], a);
            acc[t] = a;
        }
#pragma unroll
        for (int t = 0; t < 4; ++t)
#pragma unroll
            for (int j = 0; j < 4; ++j) act[t][j] = f2bf(fmaxf(acc[t][j], 0.0f));

#pragma unroll
        for (int t = 0; t < 4; ++t) {
            f32x4 a = bf3[t];
#pragma unroll
            for (int kb = 0; kb < 4; ++kb) a = mfma16(w3f[t][kb], act[kb], a);
            bf16x4 o;
#pragma unroll
            for (int j = 0; j < 4; ++j) o[j] = f2bf(a[j]);
            if (e < E)
                *reinterpret_cast<bf16x4*>(eout + (size_t)e * 64 + t * 16 + g * 4) = o;
        }
    }
}

// ---------------------------------------------------------------------------
// Node embedding MLP via MFMA: x:[N,4] f32 -> h:[N,64] bf16.
// Same fragment chain as edge_mlp; layer-1 K=4 real (rest zero).
// ---------------------------------------------------------------------------
__global__ __launch_bounds__(256) void node_mlp_mfma(
    const float* __restrict__ x,
    const float* __restrict__ W1, const float* __restrict__ b1,
    const float* __restrict__ W2, const float* __restrict__ b2,
    const float* __restrict__ W3, const float* __restrict__ b3,
    short* __restrict__ hout, int N)
{
    const int lane = threadIdx.x & 63;
    const int el   = lane & 15;
    const int g    = lane >> 6 == 0 ? (lane >> 4) : 0;  // lane>>4, explicit

    bf16x4 w1f[4];
    bf16x4 w2f[4][4];
    bf16x4 w3f[4][4];
    f32x4  bf1[4], bf2[4], bf3[4];
#pragma unroll
    for (int t = 0; t < 4; ++t) {
        const int c = t * 16 + el;
#pragma unroll
        for (int j = 0; j < 4; ++j) {
            const int k = g * 4 + j;
            w1f[t][j] = (k < 4) ? f2bf(W1[k * 64 + c]) : (short)0;
        }
#pragma unroll
        for (int kb = 0; kb < 4; ++kb) {
#pragma unroll
            for (int j = 0; j < 4; ++j) {
                const int k = kb * 16 + g * 4 + j;
                w2f[t][kb][j] = f2bf(W2[k * 64 + c]);
                w3f[t][kb][j] = f2bf(W3[k * 64 + c]);
            }
        }
        const float4 v1 = *reinterpret_cast<const float4*>(b1 + t * 16 + g * 4);
        const float4 v2 = *reinterpret_cast<const float4*>(b2 + t * 16 + g * 4);
        const float4 v3 = *reinterpret_cast<const float4*>(b3 + t * 16 + g * 4);
        bf1[t][0] = v1.x; bf1[t][1] = v1.y; bf1[t][2] = v1.z; bf1[t][3] = v1.w;
        bf2[t][0] = v2.x; bf2[t][1] = v2.y; bf2[t][2] = v2.z; bf2[t][3] = v2.w;
        bf3[t][0] = v3.x; bf3[t][1] = v3.y; bf3[t][2] = v3.z; bf3[t][3] = v3.w;
    }

    const int nblk = (N + 15) >> 4;
    const int wid  = (int)((blockIdx.x * blockDim.x + threadIdx.x) >> 6);
    const int nw   = (int)((gridDim.x * blockDim.x) >> 6);

    for (int nb = wid; nb < nblk; nb += nw) {
        const int n  = nb * 16 + el;
        const int nc = min(n, N - 1);

        bf16x4 bfr = (bf16x4)0;
        if (g == 0) {
            const float4 xv = *reinterpret_cast<const float4*>(x + (size_t)nc * 4);
            bfr[0] = f2bf(xv.x); bfr[1] = f2bf(xv.y);
            bfr[2] = f2bf(xv.z); bfr[3] = f2bf(xv.w);
        }

        f32x4  acc[4];
        bf16x4 act[4];
#pragma unroll
        for (int t = 0; t < 4; ++t) acc[t] = mfma16(w1f[t], bfr, bf1[t]);
#pragma unroll
        for (int t = 0; t < 4; ++t)
#pragma unroll
            for (int j = 0; j < 4; ++j) act[t][j] = f2bf(fmaxf(acc[t][j], 0.0f));

#pragma unroll
        for (int t = 0; t < 4; ++t) {
            f32x4 a = bf2[t];
#pragma unroll
            for (int kb = 0; kb < 4; ++kb) a = mfma16(w2f[t][kb], act[kb], a);
            acc[t] = a;
        }
#pragma unroll
        for (int t = 0; t < 4; ++t)
#pragma unroll
            for (int j = 0; j < 4; ++j) act[t][j] = f2bf(fmaxf(acc[t][j], 0.0f));

#pragma unroll
        for (int t = 0; t < 4; ++t) {
            f32x4 a = bf3[t];
#pragma unroll
            for (int kb = 0; kb < 4; ++kb) a = mfma16(w3f[t][kb], act[kb], a);
            bf16x4 o;
#pragma unroll
            for (int j = 0; j < 4; ++j) o[j] = f2bf(a[j]);
            if (n < N)
                *reinterpret_cast<bf16x4*>(hout + (size_t)n * 64 + t * 16 + g * 4) = o;
        }
    }
}

// ---------------------------------------------------------------------------
// Aggregation only: z = (1+eps)*h + segment_max(leaky(h[src]+ea)) as bf16.
// src comes from pack[].x (dst-sorted). 16 edges in flight (clamp-to-last).
// ---------------------------------------------------------------------------
__global__ __launch_bounds__(256) void agg_kernel(
    const short* __restrict__ h_in, short* __restrict__ z_out,
    const int* __restrict__ rowptr, const int2* __restrict__ pack,
    const short* __restrict__ ea,
    const float* __restrict__ geps, int l, int N)
{
    const int lane = threadIdx.x & 63;
    const int g    = lane >> 4;
    const int el   = lane & 15;
    const float ope = 1.0f + geps[l];

    const int nwave = gridDim.x * 4;
    const int w     = blockIdx.x * 4 + (threadIdx.x >> 6);
    const int chunk = (N + nwave - 1) / nwave;
    const int n0 = w * chunk;
    const int n1 = min(N, n0 + chunk);
    if (n0 >= n1) return;

    int r0 = rowptr[n0];
    for (int n = n0; n < n1; ++n) {
        const int r1 = rowptr[n + 1];

        float m0 = -INFINITY, m1 = -INFINITY, m2 = -INFINITY, m3 = -INFINITY;
        for (int r = r0; r < r1; r += 16) {
#pragma unroll
            for (int u = 0; u < 4; ++u) {
                const int rc = min(r + u * 4 + g, r1 - 1);
                const int s  = pack[rc].x;
                const bf16x4 hv = *reinterpret_cast<const bf16x4*>(h_in + (size_t)s * 64 + el * 4);
                const bf16x4 ev = *reinterpret_cast<const bf16x4*>(ea + (size_t)rc * 64 + el * 4);
                float c0 = bf2f(hv[0]) + bf2f(ev[0]);
                float c1 = bf2f(hv[1]) + bf2f(ev[1]);
                float c2 = bf2f(hv[2]) + bf2f(ev[2]);
                float c3 = bf2f(hv[3]) + bf2f(ev[3]);
                c0 = LRELU(c0); c1 = LRELU(c1); c2 = LRELU(c2); c3 = LRELU(c3);
                m0 = fmaxf(m0, c0); m1 = fmaxf(m1, c1);
                m2 = fmaxf(m2, c2); m3 = fmaxf(m3, c3);
            }
        }
        m0 = fmaxf(m0, __shfl_xor(m0, 16)); m0 = fmaxf(m0, __shfl_xor(m0, 32));
        m1 = fmaxf(m1, __shfl_xor(m1, 16)); m1 = fmaxf(m1, __shfl_xor(m1, 32));
        m2 = fmaxf(m2, __shfl_xor(m2, 16)); m2 = fmaxf(m2, __shfl_xor(m2, 32));
        m3 = fmaxf(m3, __shfl_xor(m3, 16)); m3 = fmaxf(m3, __shfl_xor(m3, 32));

        if (g == 0) {
            const bf16x4 hn = *reinterpret_cast<const bf16x4*>(h_in + (size_t)n * 64 + el * 4);
            bf16x4 zo;
            zo[0] = f2bf(ope * bf2f(hn[0]) + ((m0 == -INFINITY) ? 0.0f : m0));
            zo[1] = f2bf(ope * bf2f(hn[1]) + ((m1 == -INFINITY) ? 0.0f : m1));
            zo[2] = f2bf(ope * bf2f(hn[2]) + ((m2 == -INFINITY) ? 0.0f : m2));
            zo[3] = f2bf(ope * bf2f(hn[3]) + ((m3 == -INFINITY) ? 0.0f : m3));
            *reinterpret_cast<bf16x4*>(z_out + (size_t)n * 64 + el * 4) = zo;
        }
        r0 = r1;
    }
}

// ---------------------------------------------------------------------------
// GINE node MLP via MFMA (16 nodes/wave-iter) + graph pooling.
// ---------------------------------------------------------------------------
__global__ __launch_bounds__(256) void mlp_pool_kernel(
    const short* __restrict__ z, short* __restrict__ h_out,
    const int* __restrict__ batch,
    const float* __restrict__ gW1, const float* __restrict__ gb1,
    const float* __restrict__ gW2, const float* __restrict__ gb2,
    unsigned* __restrict__ pooled, int l, int N)
{
    const int lane = threadIdx.x & 63;
    const int el   = lane & 15;
    const int g    = lane >> 4;

    const float* W1 = gW1 + (size_t)l * 4096;
    const float* W2 = gW2 + (size_t)l * 4096;
    bf16x4 w1f[4][4], w2f[4][4];
    f32x4  bA[4], bB[4];
#pragma unroll
    for (int t = 0; t < 4; ++t) {
        const int c = t * 16 + el;
#pragma unroll
        for (int kb = 0; kb < 4; ++kb) {
#pragma unroll
            for (int j = 0; j < 4; ++j) {
                const int k = kb * 16 + g * 4 + j;
                w1f[t][kb][j] = f2bf(W1[k * 64 + c]);
                w2f[t][kb][j] = f2bf(W2[k * 64 + c]);
            }
        }
        const float4 v1 = *reinterpret_cast<const float4*>(gb1 + l * 64 + t * 16 + g * 4);
        const float4 v2 = *reinterpret_cast<const float4*>(gb2 + l * 64 + t * 16 + g * 4);
        bA[t][0] = v1.x; bA[t][1] = v1.y; bA[t][2] = v1.z; bA[t][3] = v1.w;
        bB[t][0] = v2.x; bB[t][1] = v2.y; bB[t][2] = v2.z; bB[t][3] = v2.w;
    }

    const int nblk = (N + 15) >> 4;
    const int wid  = (int)((blockIdx.x * blockDim.x + threadIdx.x) >> 6);
    const int nw   = (int)((gridDim.x * blockDim.x) >> 6);

    for (int nb = wid; nb < nblk; nb += nw) {
        const int n  = nb * 16 + el;
        const bool valid = (n < N);
        const int nc = valid ? n : (N - 1);

        bf16x4 zf[4];
#pragma unroll
        for (int kb = 0; kb < 4; ++kb)
            zf[kb] = *reinterpret_cast<const bf16x4*>(z + (size_t)nc * 64 + kb * 16 + g * 4);

        f32x4  acc[4];
        bf16x4 act[4];
#pragma unroll
        for (int t = 0; t < 4; ++t) {
            f32x4 a = bA[t];
#pragma unroll
            for (int kb = 0; kb < 4; ++kb) a = mfma16(w1f[t][kb], zf[kb], a);
            acc[t] = a;
        }
#pragma unroll
        for (int t = 0; t < 4; ++t)
#pragma unroll
            for (int j = 0; j < 4; ++j) act[t][j] = f2bf(LRELU(acc[t][j]));

#pragma unroll
        for (int t = 0; t < 4; ++t) {
            f32x4 a = bB[t];
#pragma unroll
            for (int kb = 0; kb < 4; ++kb) a = mfma16(w2f[t][kb], act[kb], a);
            acc[t] = a;
        }

#pragma unroll
        for (int t = 0; t < 4; ++t) {
            bf16x4 o;
#pragma unroll
            for (int j = 0; j < 4; ++j) o[j] = f2bf(acc[t][j]);
            if (valid)
                *reinterpret_cast<bf16x4*>(h_out + (size_t)n * 64 + t * 16 + g * 4) = o;
        }

        // ---- pooling ----
        const int gbl = batch[nc];
        const int gb_first = __shfl(gbl, 0);
        const int gb_last  = __shfl(gbl, 15);
        if (gb_first == gb_last) {
#pragma unroll
            for (int t = 0; t < 4; ++t) {
#pragma unroll
                for (int j = 0; j < 4; ++j) {
                    float v = valid ? acc[t][j] : -INFINITY;
                    v = fmaxf(v, __shfl_xor(v, 1));
                    v = fmaxf(v, __shfl_xor(v, 2));
                    v = fmaxf(v, __shfl_xor(v, 4));
                    v = fmaxf(v, __shfl_xor(v, 8));
                    if (el == 0)
                        atomicMax(&pooled[gb_first * 192 + l * 64 + t * 16 + g * 4 + j], fenc(v));
                }
            }
        } else if (valid) {
#pragma unroll
            for (int t = 0; t < 4; ++t)
#pragma unroll
                for (int j = 0; j < 4; ++j)
                    atomicMax(&pooled[gbl * 192 + l * 64 + t * 16 + g * 4 + j], fenc(acc[t][j]));
        }
    }
}

// ---------------------------------------------------------------------------
// Output head
// ---------------------------------------------------------------------------
__global__ __launch_bounds__(192) void out_kernel(
    const unsigned* __restrict__ pooled,
    const float* __restrict__ oW1, const float* __restrict__ ob1,
    const float* __restrict__ ogamma, const float* __restrict__ obeta,
    const float* __restrict__ oW2, const float* __restrict__ ob2,
    float* __restrict__ out)
{
    __shared__ float hp[192];
    __shared__ float partial[3];
    const int c = threadIdx.x;
    const int g = blockIdx.x;

    const unsigned u = pooled[g * 192 + c];
    hp[c] = (u == 0u) ? -INFINITY : fdec(u);
    __syncthreads();

    float y = ob1[c];
#pragma unroll 4
    for (int k = 0; k < 192; ++k)
        y += hp[k] * oW1[k * 192 + c];
    y = ogamma[c] * y + obeta[c];
    y = LRELU(y);
    float contrib = y * oW2[c];

#pragma unroll
    for (int off = 32; off > 0; off >>= 1)
        contrib += __shfl_xor(contrib, off);
    if ((threadIdx.x & 63) == 0) partial[threadIdx.x >> 6] = contrib;
    __syncthreads();
    if (threadIdx.x == 0) {
        const float logit = partial[0] + partial[1] + partial[2] + ob2[0];
        out[g] = logit;
        out[128 + g] = 1.0f / (1.0f + expf(-logit));
    }
}

extern "C" void kernel_launch(void* const* d_in, const int* in_sizes, int n_in,
                              void* d_out, int out_size, void* d_ws, size_t ws_size,
                              hipStream_t stream)
{
    const float* x     = (const float*)d_in[0];
    const int*   ei    = (const int*)d_in[1];
    const int*   batch = (const int*)d_in[2];
    const float* eattr = (const float*)d_in[3];
    const float* nW1 = (const float*)d_in[4],  *nb1 = (const float*)d_in[5];
    const float* nW2 = (const float*)d_in[6],  *nb2 = (const float*)d_in[7];
    const float* nW3 = (const float*)d_in[8],  *nb3 = (const float*)d_in[9];
    const float* eW1 = (const float*)d_in[10], *eb1 = (const float*)d_in[11];
    const float* eW2 = (const float*)d_in[12], *eb2 = (const float*)d_in[13];
    const float* eW3 = (const float*)d_in[14], *eb3 = (const float*)d_in[15];
    const float* geps = (const float*)d_in[16];
    const float* gW1 = (const float*)d_in[17], *gb1 = (const float*)d_in[18];
    const float* gW2 = (const float*)d_in[19], *gb2 = (const float*)d_in[20];
    const float* oW1 = (const float*)d_in[21], *ob1 = (const float*)d_in[22];
    const float* ogamma = (const float*)d_in[23], *obeta = (const float*)d_in[24];
    const float* oW2 = (const float*)d_in[25], *ob2 = (const float*)d_in[26];
    float* out = (float*)d_out;

    const int N = in_sizes[0] / 4;   // 100000
    const int E = in_sizes[3] / 8;   // 1600000
    const size_t EP = ((size_t)E + 15) & ~(size_t)15;

    // ---- workspace layout (256B-aligned slices) ----
    char* ws = (char*)d_ws;
    size_t off = 0;
    auto take = [&](size_t bytes) { char* p = ws + off; off += (bytes + 255) & ~(size_t)255; return p; };
    short*    ea     = (short*)take(EP * 64 * sizeof(short));            // 204.8 MB
    short*    h0     = (short*)take((size_t)N * 64 * sizeof(short));     // 12.8 MB
    short*    h1     = (short*)take((size_t)N * 64 * sizeof(short));     // 12.8 MB
    int2*     pack   = (int2*)take((size_t)E * sizeof(int2));            // 12.8 MB
    short*    zbuf   = (short*)take((size_t)N * 64 * sizeof(short));     // 12.8 MB
    int*      rowptr = (int*)take(((size_t)N + 1) * sizeof(int));
    unsigned* pooled = (unsigned*)take(128 * 192 * sizeof(unsigned));
    // deg/cursor alias h1 (dead until mlp_pool layer 0 writes it, which is
    // after scatter's last cursor use).
    int* deg    = (int*)h1;
    int* cursor = (int*)((char*)h1 + (((size_t)N * sizeof(int) + 255) & ~(size_t)255));
    (void)ws_size;

    hipMemsetAsync(pooled, 0, 128 * 192 * sizeof(unsigned), stream);
    hipMemsetAsync(deg, 0, (size_t)N * sizeof(int), stream);

    hist_kernel<<<2048, 256, 0, stream>>>(ei, deg, E);
    scan_kernel<<<1, 1024, 0, stream>>>(deg, rowptr, cursor, N);
    node_mlp_mfma<<<1024, 256, 0, stream>>>(x, nW1, nb1, nW2, nb2, nW3, nb3, h0, N);
    scatter_kernel<<<2048, 256, 0, stream>>>(ei, cursor, pack, E);
    edge_mlp_mfma<<<2048, 256, 0, stream>>>(eattr, pack, eW1, eb1, eW2, eb2, eW3, eb3, ea, E);

    for (int l = 0; l < 3; ++l) {
        const short* hi = (l & 1) ? h1 : h0;
        short*       ho = (l & 1) ? h0 : h1;
        agg_kernel<<<2048, 256, 0, stream>>>(hi, zbuf, rowptr, pack, ea, geps, l, N);
        mlp_pool_kernel<<<1024, 256, 0, stream>>>(zbuf, ho, batch,
                                                  gW1, gb1, gW2, gb2, pooled, l, N);
    }

    out_kernel<<<128, 192, 0, stream>>>(pooled, oW1, ob1, ogamma, obeta, oW2, ob2, out);
}

// Round 7
// 712.071 us; speedup vs baseline: 1.0874x; 1.0874x over previous
//
#include <hip/hip_runtime.h>
#include <hip/hip_bf16.h>

#define LRELU(x) ((x) > 0.0f ? (x) : 0.01f * (x))

typedef __attribute__((ext_vector_type(4))) short bf16x4;
typedef __attribute__((ext_vector_type(4))) float f32x4;

// Monotonic float -> uint encoding for max-atomics on pooled.
__device__ __forceinline__ unsigned fenc(float f) {
    unsigned u = __float_as_uint(f);
    return (u & 0x80000000u) ? ~u : (u | 0x80000000u);
}
__device__ __forceinline__ float fdec(unsigned u) {
    return (u & 0x80000000u) ? __uint_as_float(u & 0x7fffffffu) : __uint_as_float(~u);
}
// f32 -> bf16 RNE via HIP intrinsic (compiler pairs into v_cvt_pk_bf16_f32)
__device__ __forceinline__ short f2bf(float f) {
    __hip_bfloat16 b = __float2bfloat16(f);
    return *reinterpret_cast<short*>(&b);
}
__device__ __forceinline__ float bf2f(short s) {
    return __uint_as_float(((unsigned)(unsigned short)s) << 16);
}

__device__ __forceinline__ f32x4 mfma16(bf16x4 a, bf16x4 b, f32x4 c) {
#if __has_builtin(__builtin_amdgcn_mfma_f32_16x16x16bf16_1k)
    return __builtin_amdgcn_mfma_f32_16x16x16bf16_1k(a, b, c, 0, 0, 0);
#else
    asm("v_mfma_f32_16x16x16_bf16 %0, %1, %2, %0" : "+v"(c) : "v"(a), "v"(b));
    return c;
#endif
}

// ---------------------------------------------------------------------------
// CSR build step 1: histogram of dst INTO PADDED COUNTERS (1 per 16B) and
// record each edge's rank within its dst bucket (the atomicAdd return —
// we pay the atomic chain once, here, and never again).
// ---------------------------------------------------------------------------
__global__ __launch_bounds__(256) void hist_kernel(const int* __restrict__ ei,
                                                   int* __restrict__ deg_p,
                                                   int* __restrict__ rank, int E)
{
    const int stride = gridDim.x * blockDim.x * 4;
    const bool vec = ((E & 3) == 0);
    for (int e4 = (blockIdx.x * blockDim.x + threadIdx.x) * 4; e4 < E; e4 += stride) {
        if (vec && e4 + 3 < E) {
            const int4 d = *reinterpret_cast<const int4*>(ei + E + e4);
            int4 r;
            r.x = atomicAdd(&deg_p[(size_t)d.x * 4], 1);
            r.y = atomicAdd(&deg_p[(size_t)d.y * 4], 1);
            r.z = atomicAdd(&deg_p[(size_t)d.z * 4], 1);
            r.w = atomicAdd(&deg_p[(size_t)d.w * 4], 1);
            *reinterpret_cast<int4*>(rank + e4) = r;
        } else {
            for (int k = 0; k < 4 && e4 + k < E; ++k) {
                const int d = ei[E + e4 + k];
                rank[e4 + k] = atomicAdd(&deg_p[(size_t)d * 4], 1);
            }
        }
    }
}

// ---------------------------------------------------------------------------
// CSR build step 2: single-block exclusive scan over padded counters.
// ---------------------------------------------------------------------------
__global__ __launch_bounds__(1024) void scan_kernel(const int* __restrict__ deg_p,
                                                    int* __restrict__ rowptr, int N)
{
    __shared__ int wsum[16];
    __shared__ int tiletot;
    const int lane = threadIdx.x & 63;
    const int w    = threadIdx.x >> 6;
    int carry = 0;
    for (int base = 0; base < N; base += 4096) {
        const int i = base + (int)threadIdx.x * 4;
        int4 v = {0, 0, 0, 0};
        if (i < N)     v.x = deg_p[(size_t)i * 4];
        if (i + 1 < N) v.y = deg_p[(size_t)(i + 1) * 4];
        if (i + 2 < N) v.z = deg_p[(size_t)(i + 2) * 4];
        if (i + 3 < N) v.w = deg_p[(size_t)(i + 3) * 4];
        const int tot = v.x + v.y + v.z + v.w;
        int s = tot;
#pragma unroll
        for (int off = 1; off < 64; off <<= 1) {
            int t = __shfl_up(s, off);
            if (lane >= off) s += t;
        }
        if (lane == 63) wsum[w] = s;
        __syncthreads();
        if (threadIdx.x == 0) {
            int acc = 0;
#pragma unroll
            for (int k = 0; k < 16; ++k) { int t = wsum[k]; wsum[k] = acc; acc += t; }
            tiletot = acc;
        }
        __syncthreads();
        const int excl = carry + wsum[w] + (s - tot);
        int4 o;
        o.x = excl; o.y = excl + v.x; o.z = o.y + v.y; o.w = o.z + v.z;
        if (i + 3 < N) {
            *reinterpret_cast<int4*>(rowptr + i) = o;
        } else {
            if (i < N)     rowptr[i] = o.x;
            if (i + 1 < N) rowptr[i + 1] = o.y;
            if (i + 2 < N) rowptr[i + 2] = o.z;
        }
        carry += tiletot;
        __syncthreads();
    }
    if (threadIdx.x == 0) rowptr[N] = carry;
}

// ---------------------------------------------------------------------------
// ATOMIC-FREE scatter: p = rowptr[dst] + rank[e]. All loads/stores
// independent -> scattered-store bandwidth, no RMW latency chain.
// ---------------------------------------------------------------------------
__global__ __launch_bounds__(256) void scatter_kernel(
    const int* __restrict__ ei, const int* __restrict__ rank,
    const int* __restrict__ rowptr, int2* __restrict__ pack, int E)
{
    const int stride = gridDim.x * blockDim.x * 4;
    const bool vec = ((E & 3) == 0);
    for (int e4 = (blockIdx.x * blockDim.x + threadIdx.x) * 4; e4 < E; e4 += stride) {
        if (vec && e4 + 3 < E) {
            const int4 s  = *reinterpret_cast<const int4*>(ei + e4);
            const int4 d  = *reinterpret_cast<const int4*>(ei + E + e4);
            const int4 rk = *reinterpret_cast<const int4*>(rank + e4);
            pack[rowptr[d.x] + rk.x] = make_int2(s.x, e4 + 0);
            pack[rowptr[d.y] + rk.y] = make_int2(s.y, e4 + 1);
            pack[rowptr[d.z] + rk.z] = make_int2(s.z, e4 + 2);
            pack[rowptr[d.w] + rk.w] = make_int2(s.w, e4 + 3);
        } else {
            for (int k = 0; k < 4 && e4 + k < E; ++k) {
                const int e = e4 + k;
                pack[rowptr[ei[E + e]] + rank[e]] = make_int2(ei[e], e);
            }
        }
    }
}

// ---------------------------------------------------------------------------
// Edge embedding MLP via MFMA: iterates dst-sorted positions, GATHERS the
// f32 edge attrs via pack[].y, writes ea rows coalesced at the sorted index.
// D-frag: col(lane&15)=edge slot, row ch = t*16 + (lane>>4)*4 + j.
// ---------------------------------------------------------------------------
__global__ __launch_bounds__(256) void edge_mlp_mfma(
    const float* __restrict__ eattr, const int2* __restrict__ pack,
    const float* __restrict__ W1, const float* __restrict__ b1,
    const float* __restrict__ W2, const float* __restrict__ b2,
    const float* __restrict__ W3, const float* __restrict__ b3,
    short* __restrict__ eout, int E)
{
    const int lane = threadIdx.x & 63;
    const int el   = lane & 15;
    const int g    = lane >> 4;

    bf16x4 w1f[4];
    bf16x4 w2f[4][4];
    bf16x4 w3f[4][4];
    f32x4  bf1[4], bf2[4], bf3[4];
#pragma unroll
    for (int t = 0; t < 4; ++t) {
        const int c = t * 16 + el;
#pragma unroll
        for (int j = 0; j < 4; ++j) {
            const int k = g * 4 + j;
            w1f[t][j] = (k < 8) ? f2bf(W1[k * 64 + c]) : (short)0;
        }
#pragma unroll
        for (int kb = 0; kb < 4; ++kb) {
#pragma unroll
            for (int j = 0; j < 4; ++j) {
                const int k = kb * 16 + g * 4 + j;
                w2f[t][kb][j] = f2bf(W2[k * 64 + c]);
                w3f[t][kb][j] = f2bf(W3[k * 64 + c]);
            }
        }
        const float4 v1 = *reinterpret_cast<const float4*>(b1 + t * 16 + g * 4);
        const float4 v2 = *reinterpret_cast<const float4*>(b2 + t * 16 + g * 4);
        const float4 v3 = *reinterpret_cast<const float4*>(b3 + t * 16 + g * 4);
        bf1[t][0] = v1.x; bf1[t][1] = v1.y; bf1[t][2] = v1.z; bf1[t][3] = v1.w;
        bf2[t][0] = v2.x; bf2[t][1] = v2.y; bf2[t][2] = v2.z; bf2[t][3] = v2.w;
        bf3[t][0] = v3.x; bf3[t][1] = v3.y; bf3[t][2] = v3.z; bf3[t][3] = v3.w;
    }

    const int nblk = (E + 15) >> 4;
    const int wid  = (int)((blockIdx.x * blockDim.x + threadIdx.x) >> 6);
    const int nw   = (int)((gridDim.x * blockDim.x) >> 6);

    for (int eb = wid; eb < nblk; eb += nw) {
        const int e  = eb * 16 + el;
        const int ec = min(e, E - 1);
        const int eid = pack[ec].y;

        bf16x4 bfr = (bf16x4)0;
        if (g < 2) {
            const float4 av = *reinterpret_cast<const float4*>(eattr + (size_t)eid * 8 + g * 4);
            bfr[0] = f2bf(av.x); bfr[1] = f2bf(av.y);
            bfr[2] = f2bf(av.z); bfr[3] = f2bf(av.w);
        }

        f32x4  acc[4];
        bf16x4 act[4];

#pragma unroll
        for (int t = 0; t < 4; ++t) acc[t] = mfma16(w1f[t], bfr, bf1[t]);
#pragma unroll
        for (int t = 0; t < 4; ++t)
#pragma unroll
            for (int j = 0; j < 4; ++j) act[t][j] = f2bf(fmaxf(acc[t][j], 0.0f));

#pragma unroll
        for (int t = 0; t < 4; ++t) {
            f32x4 a = bf2[t];
#pragma unroll
            for (int kb = 0; kb < 4; ++kb) a = mfma16(w2f[t][kb], act[kb], a);
            acc[t] = a;
        }
#pragma unroll
        for (int t = 0; t < 4; ++t)
#pragma unroll
            for (int j = 0; j < 4; ++j) act[t][j] = f2bf(fmaxf(acc[t][j], 0.0f));

#pragma unroll
        for (int t = 0; t < 4; ++t) {
            f32x4 a = bf3[t];
#pragma unroll
            for (int kb = 0; kb < 4; ++kb) a = mfma16(w3f[t][kb], act[kb], a);
            bf16x4 o;
#pragma unroll
            for (int j = 0; j < 4; ++j) o[j] = f2bf(a[j]);
            if (e < E)
                *reinterpret_cast<bf16x4*>(eout + (size_t)e * 64 + t * 16 + g * 4) = o;
        }
    }
}

// ---------------------------------------------------------------------------
// Node embedding MLP via MFMA: x:[N,4] f32 -> h:[N,64] bf16.
// ---------------------------------------------------------------------------
__global__ __launch_bounds__(256) void node_mlp_mfma(
    const float* __restrict__ x,
    const float* __restrict__ W1, const float* __restrict__ b1,
    const float* __restrict__ W2, const float* __restrict__ b2,
    const float* __restrict__ W3, const float* __restrict__ b3,
    short* __restrict__ hout, int N)
{
    const int lane = threadIdx.x & 63;
    const int el   = lane & 15;
    const int g    = lane >> 4;

    bf16x4 w1f[4];
    bf16x4 w2f[4][4];
    bf16x4 w3f[4][4];
    f32x4  bf1[4], bf2[4], bf3[4];
#pragma unroll
    for (int t = 0; t < 4; ++t) {
        const int c = t * 16 + el;
#pragma unroll
        for (int j = 0; j < 4; ++j) {
            const int k = g * 4 + j;
            w1f[t][j] = (k < 4) ? f2bf(W1[k * 64 + c]) : (short)0;
        }
#pragma unroll
        for (int kb = 0; kb < 4; ++kb) {
#pragma unroll
            for (int j = 0; j < 4; ++j) {
                const int k = kb * 16 + g * 4 + j;
                w2f[t][kb][j] = f2bf(W2[k * 64 + c]);
                w3f[t][kb][j] = f2bf(W3[k * 64 + c]);
            }
        }
        const float4 v1 = *reinterpret_cast<const float4*>(b1 + t * 16 + g * 4);
        const float4 v2 = *reinterpret_cast<const float4*>(b2 + t * 16 + g * 4);
        const float4 v3 = *reinterpret_cast<const float4*>(b3 + t * 16 + g * 4);
        bf1[t][0] = v1.x; bf1[t][1] = v1.y; bf1[t][2] = v1.z; bf1[t][3] = v1.w;
        bf2[t][0] = v2.x; bf2[t][1] = v2.y; bf2[t][2] = v2.z; bf2[t][3] = v2.w;
        bf3[t][0] = v3.x; bf3[t][1] = v3.y; bf3[t][2] = v3.z; bf3[t][3] = v3.w;
    }

    const int nblk = (N + 15) >> 4;
    const int wid  = (int)((blockIdx.x * blockDim.x + threadIdx.x) >> 6);
    const int nw   = (int)((gridDim.x * blockDim.x) >> 6);

    for (int nb = wid; nb < nblk; nb += nw) {
        const int n  = nb * 16 + el;
        const int nc = min(n, N - 1);

        bf16x4 bfr = (bf16x4)0;
        if (g == 0) {
            const float4 xv = *reinterpret_cast<const float4*>(x + (size_t)nc * 4);
            bfr[0] = f2bf(xv.x); bfr[1] = f2bf(xv.y);
            bfr[2] = f2bf(xv.z); bfr[3] = f2bf(xv.w);
        }

        f32x4  acc[4];
        bf16x4 act[4];
#pragma unroll
        for (int t = 0; t < 4; ++t) acc[t] = mfma16(w1f[t], bfr, bf1[t]);
#pragma unroll
        for (int t = 0; t < 4; ++t)
#pragma unroll
            for (int j = 0; j < 4; ++j) act[t][j] = f2bf(fmaxf(acc[t][j], 0.0f));

#pragma unroll
        for (int t = 0; t < 4; ++t) {
            f32x4 a = bf2[t];
#pragma unroll
            for (int kb = 0; kb < 4; ++kb) a = mfma16(w2f[t][kb], act[kb], a);
            acc[t] = a;
        }
#pragma unroll
        for (int t = 0; t < 4; ++t)
#pragma unroll
            for (int j = 0; j < 4; ++j) act[t][j] = f2bf(fmaxf(acc[t][j], 0.0f));

#pragma unroll
        for (int t = 0; t < 4; ++t) {
            f32x4 a = bf3[t];
#pragma unroll
            for (int kb = 0; kb < 4; ++kb) a = mfma16(w3f[t][kb], act[kb], a);
            bf16x4 o;
#pragma unroll
            for (int j = 0; j < 4; ++j) o[j] = f2bf(a[j]);
            if (n < N)
                *reinterpret_cast<bf16x4*>(hout + (size_t)n * 64 + t * 16 + g * 4) = o;
        }
    }
}

// ---------------------------------------------------------------------------
// Aggregation only: z = (1+eps)*h + segment_max(leaky(h[src]+ea)) as bf16.
// ---------------------------------------------------------------------------
__global__ __launch_bounds__(256) void agg_kernel(
    const short* __restrict__ h_in, short* __restrict__ z_out,
    const int* __restrict__ rowptr, const int2* __restrict__ pack,
    const short* __restrict__ ea,
    const float* __restrict__ geps, int l, int N)
{
    const int lane = threadIdx.x & 63;
    const int g    = lane >> 4;
    const int el   = lane & 15;
    const float ope = 1.0f + geps[l];

    const int nwave = gridDim.x * 4;
    const int w     = blockIdx.x * 4 + (threadIdx.x >> 6);
    const int chunk = (N + nwave - 1) / nwave;
    const int n0 = w * chunk;
    const int n1 = min(N, n0 + chunk);
    if (n0 >= n1) return;

    int r0 = rowptr[n0];
    for (int n = n0; n < n1; ++n) {
        const int r1 = rowptr[n + 1];

        float m0 = -INFINITY, m1 = -INFINITY, m2 = -INFINITY, m3 = -INFINITY;
        for (int r = r0; r < r1; r += 16) {
#pragma unroll
            for (int u = 0; u < 4; ++u) {
                const int rc = min(r + u * 4 + g, r1 - 1);
                const int s  = pack[rc].x;
                const bf16x4 hv = *reinterpret_cast<const bf16x4*>(h_in + (size_t)s * 64 + el * 4);
                const bf16x4 ev = *reinterpret_cast<const bf16x4*>(ea + (size_t)rc * 64 + el * 4);
                float c0 = bf2f(hv[0]) + bf2f(ev[0]);
                float c1 = bf2f(hv[1]) + bf2f(ev[1]);
                float c2 = bf2f(hv[2]) + bf2f(ev[2]);
                float c3 = bf2f(hv[3]) + bf2f(ev[3]);
                c0 = LRELU(c0); c1 = LRELU(c1); c2 = LRELU(c2); c3 = LRELU(c3);
                m0 = fmaxf(m0, c0); m1 = fmaxf(m1, c1);
                m2 = fmaxf(m2, c2); m3 = fmaxf(m3, c3);
            }
        }
        m0 = fmaxf(m0, __shfl_xor(m0, 16)); m0 = fmaxf(m0, __shfl_xor(m0, 32));
        m1 = fmaxf(m1, __shfl_xor(m1, 16)); m1 = fmaxf(m1, __shfl_xor(m1, 32));
        m2 = fmaxf(m2, __shfl_xor(m2, 16)); m2 = fmaxf(m2, __shfl_xor(m2, 32));
        m3 = fmaxf(m3, __shfl_xor(m3, 16)); m3 = fmaxf(m3, __shfl_xor(m3, 32));

        if (g == 0) {
            const bf16x4 hn = *reinterpret_cast<const bf16x4*>(h_in + (size_t)n * 64 + el * 4);
            bf16x4 zo;
            zo[0] = f2bf(ope * bf2f(hn[0]) + ((m0 == -INFINITY) ? 0.0f : m0));
            zo[1] = f2bf(ope * bf2f(hn[1]) + ((m1 == -INFINITY) ? 0.0f : m1));
            zo[2] = f2bf(ope * bf2f(hn[2]) + ((m2 == -INFINITY) ? 0.0f : m2));
            zo[3] = f2bf(ope * bf2f(hn[3]) + ((m3 == -INFINITY) ? 0.0f : m3));
            *reinterpret_cast<bf16x4*>(z_out + (size_t)n * 64 + el * 4) = zo;
        }
        r0 = r1;
    }
}

// ---------------------------------------------------------------------------
// GINE node MLP via MFMA (16 nodes/wave-iter) + graph pooling.
// ---------------------------------------------------------------------------
__global__ __launch_bounds__(256) void mlp_pool_kernel(
    const short* __restrict__ z, short* __restrict__ h_out,
    const int* __restrict__ batch,
    const float* __restrict__ gW1, const float* __restrict__ gb1,
    const float* __restrict__ gW2, const float* __restrict__ gb2,
    unsigned* __restrict__ pooled, int l, int N)
{
    const int lane = threadIdx.x & 63;
    const int el   = lane & 15;
    const int g    = lane >> 4;

    const float* W1 = gW1 + (size_t)l * 4096;
    const float* W2 = gW2 + (size_t)l * 4096;
    bf16x4 w1f[4][4], w2f[4][4];
    f32x4  bA[4], bB[4];
#pragma unroll
    for (int t = 0; t < 4; ++t) {
        const int c = t * 16 + el;
#pragma unroll
        for (int kb = 0; kb < 4; ++kb) {
#pragma unroll
            for (int j = 0; j < 4; ++j) {
                const int k = kb * 16 + g * 4 + j;
                w1f[t][kb][j] = f2bf(W1[k * 64 + c]);
                w2f[t][kb][j] = f2bf(W2[k * 64 + c]);
            }
        }
        const float4 v1 = *reinterpret_cast<const float4*>(gb1 + l * 64 + t * 16 + g * 4);
        const float4 v2 = *reinterpret_cast<const float4*>(gb2 + l * 64 + t * 16 + g * 4);
        bA[t][0] = v1.x; bA[t][1] = v1.y; bA[t][2] = v1.z; bA[t][3] = v1.w;
        bB[t][0] = v2.x; bB[t][1] = v2.y; bB[t][2] = v2.z; bB[t][3] = v2.w;
    }

    const int nblk = (N + 15) >> 4;
    const int wid  = (int)((blockIdx.x * blockDim.x + threadIdx.x) >> 6);
    const int nw   = (int)((gridDim.x * blockDim.x) >> 6);

    for (int nb = wid; nb < nblk; nb += nw) {
        const int n  = nb * 16 + el;
        const bool valid = (n < N);
        const int nc = valid ? n : (N - 1);

        bf16x4 zf[4];
#pragma unroll
        for (int kb = 0; kb < 4; ++kb)
            zf[kb] = *reinterpret_cast<const bf16x4*>(z + (size_t)nc * 64 + kb * 16 + g * 4);

        f32x4  acc[4];
        bf16x4 act[4];
#pragma unroll
        for (int t = 0; t < 4; ++t) {
            f32x4 a = bA[t];
#pragma unroll
            for (int kb = 0; kb < 4; ++kb) a = mfma16(w1f[t][kb], zf[kb], a);
            acc[t] = a;
        }
#pragma unroll
        for (int t = 0; t < 4; ++t)
#pragma unroll
            for (int j = 0; j < 4; ++j) act[t][j] = f2bf(LRELU(acc[t][j]));

#pragma unroll
        for (int t = 0; t < 4; ++t) {
            f32x4 a = bB[t];
#pragma unroll
            for (int kb = 0; kb < 4; ++kb) a = mfma16(w2f[t][kb], act[kb], a);
            acc[t] = a;
        }

#pragma unroll
        for (int t = 0; t < 4; ++t) {
            bf16x4 o;
#pragma unroll
            for (int j = 0; j < 4; ++j) o[j] = f2bf(acc[t][j]);
            if (valid)
                *reinterpret_cast<bf16x4*>(h_out + (size_t)n * 64 + t * 16 + g * 4) = o;
        }

        // ---- pooling ----
        const int gbl = batch[nc];
        const int gb_first = __shfl(gbl, 0);
        const int gb_last  = __shfl(gbl, 15);
        if (gb_first == gb_last) {
#pragma unroll
            for (int t = 0; t < 4; ++t) {
#pragma unroll
                for (int j = 0; j < 4; ++j) {
                    float v = valid ? acc[t][j] : -INFINITY;
                    v = fmaxf(v, __shfl_xor(v, 1));
                    v = fmaxf(v, __shfl_xor(v, 2));
                    v = fmaxf(v, __shfl_xor(v, 4));
                    v = fmaxf(v, __shfl_xor(v, 8));
                    if (el == 0)
                        atomicMax(&pooled[gb_first * 192 + l * 64 + t * 16 + g * 4 + j], fenc(v));
                }
            }
        } else if (valid) {
#pragma unroll
            for (int t = 0; t < 4; ++t)
#pragma unroll
                for (int j = 0; j < 4; ++j)
                    atomicMax(&pooled[gbl * 192 + l * 64 + t * 16 + g * 4 + j], fenc(acc[t][j]));
        }
    }
}

// ---------------------------------------------------------------------------
// Output head
// ---------------------------------------------------------------------------
__global__ __launch_bounds__(192) void out_kernel(
    const unsigned* __restrict__ pooled,
    const float* __restrict__ oW1, const float* __restrict__ ob1,
    const float* __restrict__ ogamma, const float* __restrict__ obeta,
    const float* __restrict__ oW2, const float* __restrict__ ob2,
    float* __restrict__ out)
{
    __shared__ float hp[192];
    __shared__ float partial[3];
    const int c = threadIdx.x;
    const int g = blockIdx.x;

    const unsigned u = pooled[g * 192 + c];
    hp[c] = (u == 0u) ? -INFINITY : fdec(u);
    __syncthreads();

    float y = ob1[c];
#pragma unroll 4
    for (int k = 0; k < 192; ++k)
        y += hp[k] * oW1[k * 192 + c];
    y = ogamma[c] * y + obeta[c];
    y = LRELU(y);
    float contrib = y * oW2[c];

#pragma unroll
    for (int off = 32; off > 0; off >>= 1)
        contrib += __shfl_xor(contrib, off);
    if ((threadIdx.x & 63) == 0) partial[threadIdx.x >> 6] = contrib;
    __syncthreads();
    if (threadIdx.x == 0) {
        const float logit = partial[0] + partial[1] + partial[2] + ob2[0];
        out[g] = logit;
        out[128 + g] = 1.0f / (1.0f + expf(-logit));
    }
}

extern "C" void kernel_launch(void* const* d_in, const int* in_sizes, int n_in,
                              void* d_out, int out_size, void* d_ws, size_t ws_size,
                              hipStream_t stream)
{
    const float* x     = (const float*)d_in[0];
    const int*   ei    = (const int*)d_in[1];
    const int*   batch = (const int*)d_in[2];
    const float* eattr = (const float*)d_in[3];
    const float* nW1 = (const float*)d_in[4],  *nb1 = (const float*)d_in[5];
    const float* nW2 = (const float*)d_in[6],  *nb2 = (const float*)d_in[7];
    const float* nW3 = (const float*)d_in[8],  *nb3 = (const float*)d_in[9];
    const float* eW1 = (const float*)d_in[10], *eb1 = (const float*)d_in[11];
    const float* eW2 = (const float*)d_in[12], *eb2 = (const float*)d_in[13];
    const float* eW3 = (const float*)d_in[14], *eb3 = (const float*)d_in[15];
    const float* geps = (const float*)d_in[16];
    const float* gW1 = (const float*)d_in[17], *gb1 = (const float*)d_in[18];
    const float* gW2 = (const float*)d_in[19], *gb2 = (const float*)d_in[20];
    const float* oW1 = (const float*)d_in[21], *ob1 = (const float*)d_in[22];
    const float* ogamma = (const float*)d_in[23], *obeta = (const float*)d_in[24];
    const float* oW2 = (const float*)d_in[25], *ob2 = (const float*)d_in[26];
    float* out = (float*)d_out;

    const int N = in_sizes[0] / 4;   // 100000
    const int E = in_sizes[3] / 8;   // 1600000
    const size_t EP = ((size_t)E + 15) & ~(size_t)15;

    // ---- workspace layout (256B-aligned slices) ----
    char* ws = (char*)d_ws;
    size_t off = 0;
    auto take = [&](size_t bytes) { char* p = ws + off; off += (bytes + 255) & ~(size_t)255; return p; };
    short*    ea     = (short*)take(EP * 64 * sizeof(short));            // 204.8 MB
    short*    h0     = (short*)take((size_t)N * 64 * sizeof(short));     // 12.8 MB
    short*    h1     = (short*)take((size_t)N * 64 * sizeof(short));     // 12.8 MB
    int2*     pack   = (int2*)take((size_t)E * sizeof(int2));            // 12.8 MB
    short*    zbuf   = (short*)take((size_t)N * 64 * sizeof(short));     // 12.8 MB
    int*      rank   = (int*)take((size_t)E * sizeof(int));              // 6.4 MB
    int*      rowptr = (int*)take(((size_t)N + 1) * sizeof(int));
    unsigned* pooled = (unsigned*)take(128 * 192 * sizeof(unsigned));
    // deg_p (padded: 1 counter per 16B = 1.6 MB) aliases h1, which is dead
    // until mlp_pool layer 0 writes it (after scan's last deg_p use).
    int* deg_p = (int*)h1;
    (void)ws_size;

    hipMemsetAsync(pooled, 0, 128 * 192 * sizeof(unsigned), stream);
    hipMemsetAsync(deg_p, 0, (size_t)N * 4 * sizeof(int), stream);

    const int gEdge = (E / 4 + 255) / 256 + 1;
    hist_kernel<<<gEdge, 256, 0, stream>>>(ei, deg_p, rank, E);
    scan_kernel<<<1, 1024, 0, stream>>>(deg_p, rowptr, N);
    node_mlp_mfma<<<1024, 256, 0, stream>>>(x, nW1, nb1, nW2, nb2, nW3, nb3, h0, N);
    scatter_kernel<<<gEdge, 256, 0, stream>>>(ei, rank, rowptr, pack, E);
    edge_mlp_mfma<<<2048, 256, 0, stream>>>(eattr, pack, eW1, eb1, eW2, eb2, eW3, eb3, ea, E);

    for (int l = 0; l < 3; ++l) {
        const short* hi = (l & 1) ? h1 : h0;
        short*       ho = (l & 1) ? h0 : h1;
        agg_kernel<<<2048, 256, 0, stream>>>(hi, zbuf, rowptr, pack, ea, geps, l, N);
        mlp_pool_kernel<<<1024, 256, 0, stream>>>(zbuf, ho, batch,
                                                  gW1, gb1, gW2, gb2, pooled, l, N);
    }

    out_kernel<<<128, 192, 0, stream>>>(pooled, oW1, ob1, ogamma, obeta, oW2, ob2, out);
}